// Round 1
// baseline (29443.390 us; speedup 1.0000x reference)
//
#include <hip/hip_runtime.h>
#include <hip/hip_bf16.h>

// ---------------------------------------------------------------------------
// Fused LSTM (B=32,T=2048,I=128,H=512,O=128) as ONE persistent kernel.
//
// Decomposition: 8 batch-groups x 4 batches. Each group = 32 WGs; WG owns 16
// hidden units (all 4 gate types) + a 4-wide slice of the decode output.
// W_cat = [W_hh | W_ih] rows live in VGPRs as split-bf16 (hi+lo) MFMA A-frags,
// loaded once. Per step: stage [h|x] to LDS (bf16 hi/lo), 60 MFMAs/wave,
// elementwise update, fused decode of step t-1, then a group-local (32-WG)
// flag barrier with device-scope acquire/release.
//
// Sync correctness: flags are SIGNED ints; ws poison 0xAAAAAAAA is negative,
// so polls for flag >= t+1 never pass spuriously. Double-buffered h/c: buffer
// parity x is last read at step x+1; overwrite happens at step x+2 only after
// all flags show step x+1 complete.
// ---------------------------------------------------------------------------

#define B_ 32
#define T_ 2048
#define I_ 128
#define H_ 512
#define O_ 128
#define NG 8     // batch groups
#define BPG 4    // batches per group
#define WPG 32   // workgroups per group
#define NWG 256
#define NTHR 256

#define HXS 648  // LDS [h|x] row stride in bf16 elems (640 data + 8 pad)
#define CPS 520  // LDS c_prev / lin_W row stride in floats (512 + 8 pad)

typedef short bf16x8 __attribute__((ext_vector_type(8)));
typedef float f32x4 __attribute__((ext_vector_type(4)));

__device__ __forceinline__ unsigned short f2bf(float f) {
  unsigned u = __float_as_uint(f);
  u = u + 0x7FFFu + ((u >> 16) & 1u);  // round-to-nearest-even
  return (unsigned short)(u >> 16);
}
__device__ __forceinline__ float bf2f(unsigned short h) {
  return __uint_as_float(((unsigned)h) << 16);
}
__device__ __forceinline__ float sigm(float x) { return 1.0f / (1.0f + __expf(-x)); }

__global__ __launch_bounds__(NTHR, 2) void lstm_fused(
    const float* __restrict__ data, const float* __restrict__ h0,
    const float* __restrict__ c0, const float* __restrict__ W_ih,
    const float* __restrict__ W_hh, const float* __restrict__ b_ih,
    const float* __restrict__ b_hh, const float* __restrict__ lin_W,
    const float* __restrict__ lin_b, float* __restrict__ out,
    float* __restrict__ ws) {
  __shared__ alignas(16) unsigned short sHxHi[BPG * HXS];
  __shared__ alignas(16) unsigned short sHxLo[BPG * HXS];
  __shared__ alignas(16) float sCprev[BPG * CPS];
  __shared__ alignas(16) float sLinW[4 * CPS];
  __shared__ alignas(16) float sGates[16 * BPG * 4];  // [u'][b][gate]
  __shared__ alignas(16) float sCst[16 * BPG];        // [u'][b] cell state
  __shared__ float sLinB[4];

  const int bid = blockIdx.x;
  const int g = bid & 7;        // batch group (XCD-affine under bid%8 heuristic)
  const int wgi = bid >> 3;     // wg index within group, 0..31
  const int b0 = g * BPG;
  const int ubase = wgi * 16;   // global hidden-unit base for this WG
  const int tid = threadIdx.x;
  const int lane = tid & 63, wv = tid >> 6;  // wave wv = gate type (i,f,g,o)

  float* hb = ws;                          // [NG][2][BPG*H]
  float* cb = ws + NG * 2 * BPG * H_;      // [NG][2][BPG*H]
  int* flags = (int*)(ws + 2 * NG * 2 * BPG * H_);  // [NG*WPG] stride 16 ints

  // ---- one-time preload: W A-fragments (split bf16), bias, lin_W slice ----
  const int m16 = lane & 15;       // MFMA tile row = u'
  const int kc = (lane >> 4) * 8;  // k chunk base within 32-wide K step
  const int grow = wv * H_ + ubase + m16;  // global gate row in [0,2048)
  bf16x8 frAhi[20], frAlo[20];
#pragma unroll
  for (int kk = 0; kk < 20; kk++) {
    // kk<16 -> W_hh columns (k<512), kk>=16 -> W_ih columns. No straddle.
    const float* src = (kk < 16) ? (W_hh + (size_t)grow * H_ + kk * 32 + kc)
                                 : (W_ih + (size_t)grow * I_ + (kk - 16) * 32 + kc);
    float4 v0 = *(const float4*)(src);
    float4 v1 = *(const float4*)(src + 4);
    float w[8] = {v0.x, v0.y, v0.z, v0.w, v1.x, v1.y, v1.z, v1.w};
    union { unsigned short u[8]; bf16x8 v; } hi, lo;
#pragma unroll
    for (int j = 0; j < 8; j++) {
      unsigned short h = f2bf(w[j]);
      hi.u[j] = h;
      lo.u[j] = f2bf(w[j] - bf2f(h));
    }
    frAhi[kk] = hi.v;
    frAlo[kk] = lo.v;
  }
  float biasv[4];
#pragma unroll
  for (int j = 0; j < 4; j++) {
    int r = wv * H_ + ubase + (lane >> 4) * 4 + j;  // C-row for acc[j]
    biasv[j] = b_ih[r] + b_hh[r];
  }
  for (int idx = tid; idx < 4 * H_; idx += NTHR) {
    int o = idx >> 9, k = idx & (H_ - 1);
    sLinW[o * CPS + k] = lin_W[(size_t)(wgi * 4 + o) * H_ + k];
  }
  if (tid < 4) sLinB[tid] = lin_b[wgi * 4 + tid];
  if (tid < 64) {
    int up = tid >> 2, b = tid & 3;
    sCst[up * 4 + b] = c0[(size_t)(b0 + b) * H_ + ubase + up];
  }

  // B-fragment source pointers (cols b>=4 are junk: clamp to row 3, ignored)
  const int bcl = (m16 < BPG) ? m16 : (BPG - 1);
  const unsigned short* pBhi = sHxHi + bcl * HXS + kc;
  const unsigned short* pBlo = sHxLo + bcl * HXS + kc;

  for (int t = 0; t < T_; t++) {
    // ---- stage [h|x] -> LDS as bf16 hi/lo ----
    {
      int b = tid >> 6, c8 = tid & 63;  // 4 batches x 64 chunks of 8
      const float* src = (t == 0)
          ? (h0 + (size_t)(b0 + b) * H_ + c8 * 8)
          : (hb + (size_t)(g * 2 + ((t - 1) & 1)) * BPG * H_ + b * H_ + c8 * 8);
      float4 v0 = *(const float4*)src;
      float4 v1 = *(const float4*)(src + 4);
      float w[8] = {v0.x, v0.y, v0.z, v0.w, v1.x, v1.y, v1.z, v1.w};
      union { unsigned short u[8]; uint4 q; } hi, lo;
#pragma unroll
      for (int j = 0; j < 8; j++) {
        unsigned short h = f2bf(w[j]);
        hi.u[j] = h;
        lo.u[j] = f2bf(w[j] - bf2f(h));
      }
      *(uint4*)&sHxHi[b * HXS + c8 * 8] = hi.q;
      *(uint4*)&sHxLo[b * HXS + c8 * 8] = lo.q;
    }
    if (tid < 64) {  // x part: 4 batches x 16 chunks of 8
      int b = tid >> 4, c8 = tid & 15;
      const float* src = data + ((size_t)(b0 + b) * T_ + t) * I_ + c8 * 8;
      float4 v0 = *(const float4*)src;
      float4 v1 = *(const float4*)(src + 4);
      float w[8] = {v0.x, v0.y, v0.z, v0.w, v1.x, v1.y, v1.z, v1.w};
      union { unsigned short u[8]; uint4 q; } hi, lo;
#pragma unroll
      for (int j = 0; j < 8; j++) {
        unsigned short h = f2bf(w[j]);
        hi.u[j] = h;
        lo.u[j] = f2bf(w[j] - bf2f(h));
      }
      *(uint4*)&sHxHi[b * HXS + H_ + c8 * 8] = hi.q;
      *(uint4*)&sHxLo[b * HXS + H_ + c8 * 8] = lo.q;
    }
    if (t > 0) {  // stage c_{t-1} for fused decode
      for (int idx = tid; idx < BPG * (H_ / 4); idx += NTHR) {
        int b = idx >> 7, c4 = idx & 127;
        *(float4*)&sCprev[b * CPS + c4 * 4] = *(const float4*)(
            cb + (size_t)(g * 2 + ((t - 1) & 1)) * BPG * H_ + b * H_ + c4 * 4);
      }
    }
    __syncthreads();

    // ---- gates = W_cat @ [h|x] via split-bf16 MFMA (fp32-grade accuracy) ----
    f32x4 acc = {0.f, 0.f, 0.f, 0.f};
#pragma unroll
    for (int kk = 0; kk < 20; kk++) {
      bf16x8 bh = *(const bf16x8*)(pBhi + kk * 32);
      bf16x8 bl = *(const bf16x8*)(pBlo + kk * 32);
      acc = __builtin_amdgcn_mfma_f32_16x16x32_bf16(frAhi[kk], bh, acc, 0, 0, 0);
      acc = __builtin_amdgcn_mfma_f32_16x16x32_bf16(frAhi[kk], bl, acc, 0, 0, 0);
      acc = __builtin_amdgcn_mfma_f32_16x16x32_bf16(frAlo[kk], bh, acc, 0, 0, 0);
    }
    if (m16 < BPG) {  // C layout: col=lane&15 (=batch), row=(lane>>4)*4+j (=u')
#pragma unroll
      for (int j = 0; j < 4; j++) {
        int up = (lane >> 4) * 4 + j;
        sGates[(up * BPG + m16) * 4 + wv] = acc[j] + biasv[j];
      }
    }
    __syncthreads();

    // ---- elementwise LSTM cell update (64 threads) ----
    if (tid < 64) {
      int up = tid >> 2, b = tid & 3;
      const float4 gv = *(const float4*)&sGates[(up * BPG + b) * 4];  // i,f,g,o
      float ig = sigm(gv.x), fg = sigm(gv.y);
      float gg = tanhf(gv.z), og = sigm(gv.w);
      float c_new = fg * sCst[up * 4 + b] + ig * gg;
      float h_new = og * tanhf(c_new);
      sCst[up * 4 + b] = c_new;
      float* hbc = hb + (size_t)(g * 2 + (t & 1)) * BPG * H_;
      float* cbc = cb + (size_t)(g * 2 + (t & 1)) * BPG * H_;
      hbc[b * H_ + ubase + up] = h_new;
      cbc[b * H_ + ubase + up] = c_new;
      if (t == T_ - 1) {  // h_f, c_f
        const size_t DEC = (size_t)B_ * T_ * O_;
        out[DEC + (size_t)(b0 + b) * H_ + ubase + up] = h_new;
        out[DEC + (size_t)B_ * H_ + (size_t)(b0 + b) * H_ + ubase + up] = c_new;
      }
    }

    // ---- fused decode of step t-1: decoded[b,t-1, wgi*4..+4) ----
    if (t > 0) {
      int q = tid >> 4, ks = tid & 15, o = q >> 2, b = q & 3;
      float s = 0.f;
#pragma unroll
      for (int j = 0; j < 32; j++) {
        int k = ks * 32 + ((j + ks) & 31);  // rotated to avoid bank conflicts
        s += sLinW[o * CPS + k] * sCprev[b * CPS + k];
      }
      s += __shfl_xor(s, 1);
      s += __shfl_xor(s, 2);
      s += __shfl_xor(s, 4);
      s += __shfl_xor(s, 8);
      if (ks == 0)
        out[(size_t)(b0 + b) * T_ * O_ + (size_t)(t - 1) * O_ + wgi * 4 + o] =
            s + sLinB[o];
    }
    __syncthreads();  // drains vmcnt: all global writes of this WG are in L2

    // ---- group-local barrier ----
    if (tid == 0)
      __hip_atomic_store(&flags[(g * WPG + wgi) * 16], t + 1, __ATOMIC_RELEASE,
                         __HIP_MEMORY_SCOPE_AGENT);
    if (wv == 0) {
      int idx = (lane < WPG) ? lane : 0;
      for (;;) {
        int f = __hip_atomic_load(&flags[(g * WPG + idx) * 16], __ATOMIC_ACQUIRE,
                                  __HIP_MEMORY_SCOPE_AGENT);
        if (__all(f >= t + 1)) break;
        __builtin_amdgcn_s_sleep(2);
      }
    }
    __syncthreads();
  }

  // ---- epilogue: decode final step t = T-1 ----
  for (int idx = tid; idx < BPG * (H_ / 4); idx += NTHR) {
    int b = idx >> 7, c4 = idx & 127;
    *(float4*)&sCprev[b * CPS + c4 * 4] = *(const float4*)(
        cb + (size_t)(g * 2 + ((T_ - 1) & 1)) * BPG * H_ + b * H_ + c4 * 4);
  }
  __syncthreads();
  {
    int q = tid >> 4, ks = tid & 15, o = q >> 2, b = q & 3;
    float s = 0.f;
#pragma unroll
    for (int j = 0; j < 32; j++) {
      int k = ks * 32 + ((j + ks) & 31);
      s += sLinW[o * CPS + k] * sCprev[b * CPS + k];
    }
    s += __shfl_xor(s, 1);
    s += __shfl_xor(s, 2);
    s += __shfl_xor(s, 4);
    s += __shfl_xor(s, 8);
    if (ks == 0)
      out[(size_t)(b0 + b) * T_ * O_ + (size_t)(T_ - 1) * O_ + wgi * 4 + o] =
          s + sLinB[o];
  }
}

extern "C" void kernel_launch(void* const* d_in, const int* in_sizes, int n_in,
                              void* d_out, int out_size, void* d_ws, size_t ws_size,
                              hipStream_t stream) {
  const float* data = (const float*)d_in[0];
  const float* h0 = (const float*)d_in[1];
  const float* c0 = (const float*)d_in[2];
  const float* W_ih = (const float*)d_in[3];
  const float* W_hh = (const float*)d_in[4];
  const float* b_ih = (const float*)d_in[5];
  const float* b_hh = (const float*)d_in[6];
  const float* lin_W = (const float*)d_in[7];
  const float* lin_b = (const float*)d_in[8];
  float* out = (float*)d_out;
  float* ws = (float*)d_ws;

  hipLaunchKernelGGL(lstm_fused, dim3(NWG), dim3(NTHR), 0, stream, data, h0, c0,
                     W_ih, W_hh, b_ih, b_hh, lin_W, lin_b, out, ws);
}

// Round 2
// 15439.676 us; speedup vs baseline: 1.9070x; 1.9070x over previous
//
#include <hip/hip_runtime.h>
#include <hip/hip_bf16.h>

// ---------------------------------------------------------------------------
// v2: Fused LSTM (B=32,T=2048,I=128,H=512,O=128), one persistent kernel.
// 8 batch-groups x 4 batches; 32 WGs/group; WG = 512 threads (8 waves).
// Wave (gate, kh) = (w>>1, w&1): 16 gate-rows x K-half (320). A-frags
// (split-bf16 hi/lo) = 80 VGPRs/thread -> no spill. Partial K-sums combined
// in LDS (fp32 exact). Decode + x-prefetch run AFTER the flag release
// (off the critical path). h exchanged as pre-split bf16 hi/lo. Poll uses
// relaxed atomics + one acquire fence on detection.
//
// Sync: flags signed ints; 0xAA poison is negative -> poll f>=t+1 safe.
// Double-buffered h/c by step parity; release after last read of parity
// (t-1)&1 ensures no overwrite-before-read (peers write parity (t+1)&1
// only after all flags >= t+1).
// ---------------------------------------------------------------------------

#define B_ 32
#define T_ 2048
#define I_ 128
#define H_ 512
#define O_ 128
#define NG 8     // batch groups
#define BPG 4    // batches per group
#define WPG 32   // workgroups per group
#define NWG 256
#define NTHR 512

#define HXS 648  // LDS [h|x] row stride (bf16 elems), 640 data + 8 pad
#define CPS 520  // LDS c_prev / lin_W row stride (floats), 512 + 8 pad

typedef short bf16x8 __attribute__((ext_vector_type(8)));
typedef float f32x4 __attribute__((ext_vector_type(4)));

static __device__ __forceinline__ unsigned short f2bf(float f) {
  unsigned u = __float_as_uint(f);
  u = u + 0x7FFFu + ((u >> 16) & 1u);  // RNE
  return (unsigned short)(u >> 16);
}
static __device__ __forceinline__ float bf2f(unsigned short h) {
  return __uint_as_float(((unsigned)h) << 16);
}
static __device__ __forceinline__ float fsigm(float x) {
  return 1.0f / (1.0f + __expf(-x));
}
static __device__ __forceinline__ float ftanh(float x) {
  // 1 - 2/(e^{2x}+1): exact at +-inf, no NaN (expf overflow -> +inf -> 1)
  return 1.0f - 2.0f / (__expf(2.0f * x) + 1.0f);
}

__global__ __launch_bounds__(NTHR, 2) void lstm_fused(
    const float* __restrict__ data, const float* __restrict__ h0,
    const float* __restrict__ c0, const float* __restrict__ W_ih,
    const float* __restrict__ W_hh, const float* __restrict__ b_ih,
    const float* __restrict__ b_hh, const float* __restrict__ lin_W,
    const float* __restrict__ lin_b, float* __restrict__ out,
    float* __restrict__ ws) {
  __shared__ alignas(16) unsigned short sHxHi[BPG * HXS];
  __shared__ alignas(16) unsigned short sHxLo[BPG * HXS];
  __shared__ alignas(16) float sCprev[BPG * CPS];
  __shared__ alignas(16) float sLinW[4 * CPS];
  __shared__ alignas(16) float sGates[2 * 64 * 4];  // [kh][(up*4+b)][gate]
  __shared__ alignas(16) float sCst[64];            // [up*4+b]
  __shared__ alignas(16) float sBias[64];           // [up*4+gate]
  __shared__ float sLinB[4];

  const int bid = blockIdx.x;
  const int g = bid & 7;       // batch group -> XCD (bid%8 round-robin)
  const int wgi = bid >> 3;    // 0..31 within group
  const int b0 = g * BPG;
  const int ubase = wgi * 16;  // hidden-unit base
  const int tid = threadIdx.x;
  const int lane = tid & 63;
  const int w = tid >> 6;      // wave 0..7
  const int gate = w >> 1;     // i,f,g,o
  const int kh = w & 1;        // K half: [kh*320, kh*320+320)
  const int m16 = lane & 15;   // MFMA col = batch
  const int kcg = lane >> 4;   // k sub-chunk

  float* cb = ws;  // [NG][2][BPG][H] fp32 cell state
  unsigned short* hbHi = (unsigned short*)(cb + NG * 2 * BPG * H_);
  unsigned short* hbLo = hbHi + NG * 2 * BPG * H_;
  int* flags = (int*)(hbLo + NG * 2 * BPG * H_);  // [NWG] stride 16 ints

  // ---- one-time preload ----
  bf16x8 fAhi[10], fAlo[10];
  const int grow = gate * H_ + ubase + m16;  // gate row in [0,2048)
#pragma unroll
  for (int kk = 0; kk < 10; kk++) {
    int k = kh * 320 + kk * 32 + kcg * 8;
    const float* src = (k < H_) ? (W_hh + (size_t)grow * H_ + k)
                                : (W_ih + (size_t)grow * I_ + (k - H_));
    float4 v0 = *(const float4*)src;
    float4 v1 = *(const float4*)(src + 4);
    float w8[8] = {v0.x, v0.y, v0.z, v0.w, v1.x, v1.y, v1.z, v1.w};
    union { unsigned short u[8]; bf16x8 v; } hi, lo;
#pragma unroll
    for (int j = 0; j < 8; j++) {
      unsigned short h = f2bf(w8[j]);
      hi.u[j] = h;
      lo.u[j] = f2bf(w8[j] - bf2f(h));
    }
    fAhi[kk] = hi.v;
    fAlo[kk] = lo.v;
  }
  if (tid < 64) {  // bias: [up][gate]
    int u_ = tid >> 2, ga = tid & 3;
    int r = ga * H_ + ubase + u_;
    sBias[u_ * 4 + ga] = b_ih[r] + b_hh[r];
  }
  for (int idx = tid; idx < 4 * H_; idx += NTHR) {
    int o = idx >> 9, k = idx & (H_ - 1);
    sLinW[o * CPS + k] = lin_W[(size_t)(wgi * 4 + o) * H_ + k];
  }
  if (tid < 4) sLinB[tid] = lin_b[wgi * 4 + tid];
  if (tid >= 64 && tid < 128) {  // c0 -> sCst (separate wave from bias)
    int q = tid - 64;
    int up = q >> 2, b = q & 3;
    sCst[q] = c0[(size_t)(b0 + b) * H_ + ubase + up];
  }

  // x_0 prefetch into registers (threads 0..127 hold float4 = 4 elems)
  float4 pfx;
  if (tid < 128) {
    int b = tid >> 5, c4 = tid & 31;
    pfx = *(const float4*)(data + ((size_t)(b0 + b) * T_ + 0) * I_ + c4 * 4);
  }

  const int bcl = (m16 < BPG) ? m16 : (BPG - 1);
  const unsigned short* pBhi = sHxHi + bcl * HXS + kh * 320 + kcg * 8;
  const unsigned short* pBlo = sHxLo + bcl * HXS + kh * 320 + kcg * 8;

  for (int t = 0; t < T_; t++) {
    // ---- stage c_{t-1} (for post-release decode) ----
    if (t > 0) {
      int b = tid >> 7, c4 = tid & 127;
      *(float4*)&sCprev[b * CPS + c4 * 4] = *(const float4*)(
          cb + ((size_t)(g * 2 + ((t - 1) & 1)) * BPG + b) * H_ + c4 * 4);
    }
    // ---- stage h -> LDS (bf16 hi/lo) ----
    {
      int half = tid >> 8;          // 0: hi, 1: lo
      int e = (tid & 255) * 8;      // flat elem over [b][512]
      int b = e >> 9, off = e & 511;
      if (t == 0) {
        const float* src = h0 + (size_t)(b0 + b) * H_ + off;
        float4 v0 = *(const float4*)src;
        float4 v1 = *(const float4*)(src + 4);
        float w8[8] = {v0.x, v0.y, v0.z, v0.w, v1.x, v1.y, v1.z, v1.w};
        union { unsigned short u[8]; uint4 q; } ot;
#pragma unroll
        for (int j = 0; j < 8; j++) {
          unsigned short h = f2bf(w8[j]);
          ot.u[j] = half ? f2bf(w8[j] - bf2f(h)) : h;
        }
        *(uint4*)&(half ? sHxLo : sHxHi)[b * HXS + off] = ot.q;
      } else {
        const unsigned short* srcb =
            (half ? hbLo : hbHi) +
            ((size_t)(g * 2 + ((t - 1) & 1)) * BPG + b) * H_ + off;
        *(uint4*)&(half ? sHxLo : sHxHi)[b * HXS + off] =
            *(const uint4*)srcb;
      }
    }
    // ---- stage x_t from prefetch regs ----
    if (tid < 128) {
      int b = tid >> 5, c4 = tid & 31;
      union { unsigned short u[4]; uint2 q; } hi, lo;
      float w4[4] = {pfx.x, pfx.y, pfx.z, pfx.w};
#pragma unroll
      for (int j = 0; j < 4; j++) {
        unsigned short h = f2bf(w4[j]);
        hi.u[j] = h;
        lo.u[j] = f2bf(w4[j] - bf2f(h));
      }
      *(uint2*)&sHxHi[b * HXS + H_ + c4 * 4] = hi.q;
      *(uint2*)&sHxLo[b * HXS + H_ + c4 * 4] = lo.q;
    }
    __syncthreads();

    // ---- MFMA: partial gates for (gate, kh) ----
    f32x4 a0 = {0.f, 0.f, 0.f, 0.f}, a1 = a0, a2 = a0;
#pragma unroll
    for (int kk = 0; kk < 10; kk++) {
      bf16x8 bh = *(const bf16x8*)(pBhi + kk * 32);
      bf16x8 bl = *(const bf16x8*)(pBlo + kk * 32);
      a0 = __builtin_amdgcn_mfma_f32_16x16x32_bf16(fAhi[kk], bh, a0, 0, 0, 0);
      a1 = __builtin_amdgcn_mfma_f32_16x16x32_bf16(fAhi[kk], bl, a1, 0, 0, 0);
      a2 = __builtin_amdgcn_mfma_f32_16x16x32_bf16(fAlo[kk], bh, a2, 0, 0, 0);
    }
    if (m16 < BPG) {  // C: col=m16(batch), row=kcg*4+j (=up)
#pragma unroll
      for (int j = 0; j < 4; j++) {
        int up = kcg * 4 + j;
        sGates[(kh * 64 + up * 4 + m16) * 4 + gate] = a0[j] + a1[j] + a2[j];
      }
    }
    __syncthreads();

    // ---- elementwise cell update (wave 0) ----
    if (tid < 64) {
      int up = tid >> 2, b = tid & 3;
      const float4 p0 = *(const float4*)&sGates[(up * 4 + b) * 4];
      const float4 p1 = *(const float4*)&sGates[(64 + up * 4 + b) * 4];
      float gi = p0.x + p1.x + sBias[up * 4 + 0];
      float gf = p0.y + p1.y + sBias[up * 4 + 1];
      float gg = p0.z + p1.z + sBias[up * 4 + 2];
      float go = p0.w + p1.w + sBias[up * 4 + 3];
      float cn = fsigm(gf) * sCst[tid] + fsigm(gi) * ftanh(gg);
      float hn = fsigm(go) * ftanh(cn);
      sCst[tid] = cn;
      size_t sbase = ((size_t)(g * 2 + (t & 1)) * BPG + b) * H_ + ubase + up;
      cb[sbase] = cn;
      unsigned short hh = f2bf(hn);
      hbHi[sbase] = hh;
      hbLo[sbase] = f2bf(hn - bf2f(hh));
      if (t == T_ - 1) {
        const size_t DEC = (size_t)B_ * T_ * O_;
        out[DEC + (size_t)(b0 + b) * H_ + ubase + up] = hn;
        out[DEC + (size_t)B_ * H_ + (size_t)(b0 + b) * H_ + ubase + up] = cn;
      }
    }
    __syncthreads();  // all h/c stores drained (per-wave vmcnt at barrier)

    // ---- release: step t done ----
    if (tid == 0)
      __hip_atomic_store(&flags[(g * WPG + wgi) * 16], t + 1, __ATOMIC_RELEASE,
                         __HIP_MEMORY_SCOPE_AGENT);

    // ---- decode step t-1 (off critical path; LDS only) ----
    if (t > 0) {
      int q = tid >> 5, ks = tid & 31, o = q >> 2, b = q & 3;
      float s = 0.f;
#pragma unroll
      for (int j = 0; j < 16; j++) {
        int k = ks + j * 32;  // lane-distinct banks
        s += sLinW[o * CPS + k] * sCprev[b * CPS + k];
      }
      s += __shfl_xor(s, 1);
      s += __shfl_xor(s, 2);
      s += __shfl_xor(s, 4);
      s += __shfl_xor(s, 8);
      s += __shfl_xor(s, 16);
      if (ks == 0)
        out[((size_t)(b0 + b) * T_ + (t - 1)) * O_ + wgi * 4 + o] =
            s + sLinB[o];
    }
    // ---- prefetch x_{t+1} (latency hides under the wait) ----
    if (tid < 128) {
      int tp = (t + 1 < T_) ? t + 1 : T_ - 1;
      int b = tid >> 5, c4 = tid & 31;
      pfx = *(const float4*)(data + ((size_t)(b0 + b) * T_ + tp) * I_ + c4 * 4);
    }
    // ---- poll (wave 7): relaxed spin, one acquire fence on detect ----
    if (tid >= 448) {
      int idx = (g * WPG + (tid & 31)) * 16;
      for (;;) {
        int f = __hip_atomic_load(&flags[idx], __ATOMIC_RELAXED,
                                  __HIP_MEMORY_SCOPE_AGENT);
        if (__all(f >= t + 1)) break;
      }
      __builtin_amdgcn_fence(__ATOMIC_ACQUIRE, "agent");
    }
    __syncthreads();
  }

  // ---- epilogue: decode final step T-1 ----
  {
    int b = tid >> 7, c4 = tid & 127;
    *(float4*)&sCprev[b * CPS + c4 * 4] = *(const float4*)(
        cb + ((size_t)(g * 2 + ((T_ - 1) & 1)) * BPG + b) * H_ + c4 * 4);
  }
  __syncthreads();
  {
    int q = tid >> 5, ks = tid & 31, o = q >> 2, b = q & 3;
    float s = 0.f;
#pragma unroll
    for (int j = 0; j < 16; j++) {
      int k = ks + j * 32;
      s += sLinW[o * CPS + k] * sCprev[b * CPS + k];
    }
    s += __shfl_xor(s, 1);
    s += __shfl_xor(s, 2);
    s += __shfl_xor(s, 4);
    s += __shfl_xor(s, 8);
    s += __shfl_xor(s, 16);
    if (ks == 0)
      out[((size_t)(b0 + b) * T_ + (T_ - 1)) * O_ + wgi * 4 + o] =
          s + sLinB[o];
  }
}

extern "C" void kernel_launch(void* const* d_in, const int* in_sizes, int n_in,
                              void* d_out, int out_size, void* d_ws, size_t ws_size,
                              hipStream_t stream) {
  const float* data = (const float*)d_in[0];
  const float* h0 = (const float*)d_in[1];
  const float* c0 = (const float*)d_in[2];
  const float* W_ih = (const float*)d_in[3];
  const float* W_hh = (const float*)d_in[4];
  const float* b_ih = (const float*)d_in[5];
  const float* b_hh = (const float*)d_in[6];
  const float* lin_W = (const float*)d_in[7];
  const float* lin_b = (const float*)d_in[8];
  float* out = (float*)d_out;
  float* ws = (float*)d_ws;

  hipLaunchKernelGGL(lstm_fused, dim3(NWG), dim3(NTHR), 0, stream, data, h0, c0,
                     W_ih, W_hh, b_ih, b_hh, lin_W, lin_b, out, ws);
}

// Round 6
// 6012.181 us; speedup vs baseline: 4.8973x; 2.5681x over previous
//
#include <hip/hip_runtime.h>
#include <hip/hip_bf16.h>

// ---------------------------------------------------------------------------
// v3: Fused LSTM (B=32,T=2048,I=128,H=512,O=128), one persistent kernel.
//
// Change vs v2: eliminate ALL per-step cache-maintenance (agent release fence
// = L2 writeback, acquire fence = L1/L2 invalidate -> ~7.5us/step serialized).
// Cross-WG state (h packed bf16 hi|lo in one u32, c fp32, group counter) moves
// exclusively through RELAXED agent-scope atomics, which bypass L1/local-L2
// and are served at the device coherence point. Ordering: s_waitcnt vmcnt(0)
// before the relaxed counter increment (stores are write-through, so ACKed
// data is visible); readers' atomic loads can never see stale cache lines.
// Sync = one monotone counter per group (poll >= 32*(t+1)); counter region is
// zeroed by hipMemsetAsync before launch (ws poison otherwise breaks it).
//
// Roles per step: all 8 waves MFMA; then wave0 = cell update + release + poll,
// waves1-4 = decode step t-1 (off critical path), waves5-6 = x_{t+1} stage +
// x_{t+2} prefetch; then all stage h_t/c_t from IC into LDS.
// ---------------------------------------------------------------------------

#define B_ 32
#define T_ 2048
#define I_ 128
#define H_ 512
#define O_ 128
#define NG 8     // batch groups
#define BPG 4    // batches per group
#define WPG 32   // workgroups per group
#define NWG 256
#define NTHR 512

#define HXS 648  // LDS [h|x] row stride (bf16 elems), 640 data + 8 pad
#define CPS 520  // LDS c_prev / lin_W row stride (floats), 512 + 8 pad

typedef short bf16x8 __attribute__((ext_vector_type(8)));
typedef float f32x4 __attribute__((ext_vector_type(4)));
typedef unsigned long long u64;

static __device__ __forceinline__ unsigned f2bf(float f) {
  unsigned u = __float_as_uint(f);
  u = u + 0x7FFFu + ((u >> 16) & 1u);  // RNE
  return u >> 16;
}
static __device__ __forceinline__ float bf2f(unsigned h) {
  return __uint_as_float(h << 16);
}
static __device__ __forceinline__ float fsigm(float x) {
  return 1.0f / (1.0f + __expf(-x));
}
static __device__ __forceinline__ float ftanh(float x) {
  return 1.0f - 2.0f / (__expf(2.0f * x) + 1.0f);  // safe at +-inf
}

#define ALD(p) __hip_atomic_load((p), __ATOMIC_RELAXED, __HIP_MEMORY_SCOPE_AGENT)
#define AST(p, v) __hip_atomic_store((p), (v), __ATOMIC_RELAXED, __HIP_MEMORY_SCOPE_AGENT)

__global__ __launch_bounds__(NTHR, 2) void lstm_fused(
    const float* __restrict__ data, const float* __restrict__ h0,
    const float* __restrict__ c0, const float* __restrict__ W_ih,
    const float* __restrict__ W_hh, const float* __restrict__ b_ih,
    const float* __restrict__ b_hh, const float* __restrict__ lin_W,
    const float* __restrict__ lin_b, float* __restrict__ out,
    float* __restrict__ ws) {
  __shared__ alignas(16) unsigned short sHxHi[BPG * HXS];
  __shared__ alignas(16) unsigned short sHxLo[BPG * HXS];
  __shared__ alignas(16) float sCprev[BPG * CPS];
  __shared__ alignas(16) float sLinW[4 * CPS];
  __shared__ alignas(16) float sGates[2 * 64 * 4];  // [kh][(up*4+b)][gate]
  __shared__ alignas(16) float sCst[64];            // [up*4+b]
  __shared__ alignas(16) float sBias[64];            // [up*4+gate]
  __shared__ float sLinB[4];

  const int bid = blockIdx.x;
  const int g = bid & 7;       // batch group
  const int wgi = bid >> 3;    // 0..31 within group
  const int b0 = g * BPG;
  const int ubase = wgi * 16;  // hidden-unit base
  const int tid = threadIdx.x;
  const int lane = tid & 63;
  const int w = tid >> 6;      // wave 0..7
  const int gate = w >> 1;     // i,f,g,o
  const int kh = w & 1;        // K half
  const int m16 = lane & 15;   // MFMA col = batch
  const int kcg = lane >> 4;

  float* cb = ws;                               // [2][NG][BPG][H] fp32
  unsigned* hbPk = (unsigned*)(ws + 32768);     // [2][NG][BPG][H] (hi<<16)|lo
  int* cnt = (int*)(ws + 65536);                // [NG] stride-16 counters

  // ---- one-time preload ----
  bf16x8 fAhi[10], fAlo[10];
  const int grow = gate * H_ + ubase + m16;
#pragma unroll
  for (int kk = 0; kk < 10; kk++) {
    int k = kh * 320 + kk * 32 + kcg * 8;
    const float* src = (k < H_) ? (W_hh + (size_t)grow * H_ + k)
                                : (W_ih + (size_t)grow * I_ + (k - H_));
    float4 v0 = *(const float4*)src;
    float4 v1 = *(const float4*)(src + 4);
    float w8[8] = {v0.x, v0.y, v0.z, v0.w, v1.x, v1.y, v1.z, v1.w};
    union { unsigned short u[8]; bf16x8 v; } hi, lo;
#pragma unroll
    for (int j = 0; j < 8; j++) {
      unsigned h = f2bf(w8[j]);
      hi.u[j] = (unsigned short)h;
      lo.u[j] = (unsigned short)f2bf(w8[j] - bf2f(h));
    }
    fAhi[kk] = hi.v;
    fAlo[kk] = lo.v;
  }
  if (tid < 64) {  // bias [up][gate]
    int u_ = tid >> 2, ga = tid & 3;
    int r = ga * H_ + ubase + u_;
    sBias[u_ * 4 + ga] = b_ih[r] + b_hh[r];
  }
  if (tid >= 64 && tid < 128) {  // c0 -> sCst
    int q = tid - 64;
    sCst[q] = c0[(size_t)(b0 + (q & 3)) * H_ + ubase + (q >> 2)];
  }
  for (int idx = tid; idx < 4 * H_; idx += NTHR) {
    int o = idx >> 9, k = idx & (H_ - 1);
    sLinW[o * CPS + k] = lin_W[(size_t)(wgi * 4 + o) * H_ + k];
  }
  if (tid < 4) sLinB[tid] = lin_b[wgi * 4 + tid];

  // stage h0 (split bf16) and x0
  if (tid < 256) {
    int b = tid >> 6, off = (tid & 63) * 8;
    const float* src = h0 + (size_t)(b0 + b) * H_ + off;
    float4 v0 = *(const float4*)src;
    float4 v1 = *(const float4*)(src + 4);
    float w8[8] = {v0.x, v0.y, v0.z, v0.w, v1.x, v1.y, v1.z, v1.w};
    union { unsigned short u[8]; uint4 q; } hi, lo;
#pragma unroll
    for (int j = 0; j < 8; j++) {
      unsigned h = f2bf(w8[j]);
      hi.u[j] = (unsigned short)h;
      lo.u[j] = (unsigned short)f2bf(w8[j] - bf2f(h));
    }
    *(uint4*)&sHxHi[b * HXS + off] = hi.q;
    *(uint4*)&sHxLo[b * HXS + off] = lo.q;
  }
  if (tid >= 256 && tid < 384) {
    int i = tid - 256, b = i >> 5, c4 = i & 31;
    float4 v = *(const float4*)(data + ((size_t)(b0 + b) * T_) * I_ + c4 * 4);
    float w4[4] = {v.x, v.y, v.z, v.w};
    union { unsigned short u[4]; uint2 q; } hi, lo;
#pragma unroll
    for (int j = 0; j < 4; j++) {
      unsigned h = f2bf(w4[j]);
      hi.u[j] = (unsigned short)h;
      lo.u[j] = (unsigned short)f2bf(w4[j] - bf2f(h));
    }
    *(uint2*)&sHxHi[b * HXS + H_ + c4 * 4] = hi.q;
    *(uint2*)&sHxLo[b * HXS + H_ + c4 * 4] = lo.q;
  }
  float4 pfx;
  if (tid >= 320 && tid < 448) {  // pfx = x_1
    int i = tid - 320, b = i >> 5, c4 = i & 31;
    int tp = (T_ > 1) ? 1 : 0;
    pfx = *(const float4*)(data + ((size_t)(b0 + b) * T_ + tp) * I_ + c4 * 4);
  }
  __syncthreads();

  const int bcl = (m16 < BPG) ? m16 : (BPG - 1);
  const unsigned short* pBhi = sHxHi + bcl * HXS + kh * 320 + kcg * 8;
  const unsigned short* pBlo = sHxLo + bcl * HXS + kh * 320 + kcg * 8;

  for (int t = 0; t < T_; t++) {
    // ---- MFMA: partial gates for (gate, kh) on staged [h_{t-1}|x_t] ----
    f32x4 a0 = {0.f, 0.f, 0.f, 0.f}, a1 = a0, a2 = a0;
#pragma unroll
    for (int kk = 0; kk < 10; kk++) {
      bf16x8 bh = *(const bf16x8*)(pBhi + kk * 32);
      bf16x8 bl = *(const bf16x8*)(pBlo + kk * 32);
      a0 = __builtin_amdgcn_mfma_f32_16x16x32_bf16(fAhi[kk], bh, a0, 0, 0, 0);
      a1 = __builtin_amdgcn_mfma_f32_16x16x32_bf16(fAhi[kk], bl, a1, 0, 0, 0);
      a2 = __builtin_amdgcn_mfma_f32_16x16x32_bf16(fAlo[kk], bh, a2, 0, 0, 0);
    }
    if (m16 < BPG) {
#pragma unroll
      for (int j = 0; j < 4; j++) {
        int up = kcg * 4 + j;
        sGates[(kh * 64 + up * 4 + m16) * 4 + gate] = a0[j] + a1[j] + a2[j];
      }
    }
    __syncthreads();

    // ---- role-split post phase ----
    if (tid < 64) {
      // cell update + write-through h/c + release + poll
      int up = tid >> 2, b = tid & 3;
      const float4 p0 = *(const float4*)&sGates[(up * 4 + b) * 4];
      const float4 p1 = *(const float4*)&sGates[(64 + up * 4 + b) * 4];
      float gi = p0.x + p1.x + sBias[up * 4 + 0];
      float gf = p0.y + p1.y + sBias[up * 4 + 1];
      float gg = p0.z + p1.z + sBias[up * 4 + 2];
      float go = p0.w + p1.w + sBias[up * 4 + 3];
      float cn = fsigm(gf) * sCst[tid] + fsigm(gi) * ftanh(gg);
      float hn = fsigm(go) * ftanh(cn);
      sCst[tid] = cn;
      size_t sbase = (((size_t)(t & 1) * NG + g) * BPG + b) * H_ + ubase + up;
      AST(&cb[sbase], cn);
      unsigned hh = f2bf(hn);
      unsigned hl = f2bf(hn - bf2f(hh));
      AST(&hbPk[sbase], (hh << 16) | hl);
      if (t == T_ - 1) {
        const size_t DEC = (size_t)B_ * T_ * O_;
        out[DEC + (size_t)(b0 + b) * H_ + ubase + up] = hn;
        out[DEC + (size_t)B_ * H_ + (size_t)(b0 + b) * H_ + ubase + up] = cn;
      }
      asm volatile("s_waitcnt vmcnt(0)" ::: "memory");  // stores ACKed at IC
      if (tid == 0)
        __hip_atomic_fetch_add(&cnt[g * 16], 1, __ATOMIC_RELAXED,
                               __HIP_MEMORY_SCOPE_AGENT);
      const int target = WPG * (t + 1);
      while (ALD(&cnt[g * 16]) < target) {}
    } else if (tid < 320) {
      // decode step t-1 (LDS only, off critical path)
      if (t > 0) {
        int q = (tid >> 4) - 4;  // 0..15
        int ks = tid & 15;
        int o = q >> 2, b = q & 3;
        float s = 0.f;
#pragma unroll
        for (int j = 0; j < 32; j++) {
          int k = ks + j * 16;
          s += sLinW[o * CPS + k] * sCprev[b * CPS + k];
        }
        s += __shfl_xor(s, 1);
        s += __shfl_xor(s, 2);
        s += __shfl_xor(s, 4);
        s += __shfl_xor(s, 8);
        if (ks == 0)
          out[((size_t)(b0 + b) * T_ + (t - 1)) * O_ + wgi * 4 + o] =
              s + sLinB[o];
      }
    } else if (tid < 448) {
      // stage x_{t+1} from pfx; prefetch x_{t+2}
      int i = tid - 320, b = i >> 5, c4 = i & 31;
      union { unsigned short u[4]; uint2 q; } hi, lo;
      float w4[4] = {pfx.x, pfx.y, pfx.z, pfx.w};
#pragma unroll
      for (int j = 0; j < 4; j++) {
        unsigned h = f2bf(w4[j]);
        hi.u[j] = (unsigned short)h;
        lo.u[j] = (unsigned short)f2bf(w4[j] - bf2f(h));
      }
      *(uint2*)&sHxHi[b * HXS + H_ + c4 * 4] = hi.q;
      *(uint2*)&sHxLo[b * HXS + H_ + c4 * 4] = lo.q;
      int tp = (t + 2 < T_) ? t + 2 : T_ - 1;
      pfx = *(const float4*)(data + ((size_t)(b0 + b) * T_ + tp) * I_ + c4 * 4);
    }
    __syncthreads();

    // ---- stage h_t, c_t from IC (atomic relaxed, bypasses stale caches) ----
    {
      int b = tid >> 7, u4 = (tid & 127) * 4;
      const size_t hbase = (((size_t)(t & 1) * NG + g) * BPG + b) * H_ + u4;
      u64 q0 = ALD((u64*)&hbPk[hbase]);
      u64 q1 = ALD((u64*)&hbPk[hbase + 2]);
      unsigned v0 = (unsigned)q0, v1 = (unsigned)(q0 >> 32);
      unsigned v2 = (unsigned)q1, v3 = (unsigned)(q1 >> 32);
      uint2 hw = {(v0 >> 16) | (v1 & 0xFFFF0000u),
                  (v2 >> 16) | (v3 & 0xFFFF0000u)};
      uint2 lw = {(v0 & 0xFFFFu) | ((v1 & 0xFFFFu) << 16),
                  (v2 & 0xFFFFu) | ((v3 & 0xFFFFu) << 16)};
      *(uint2*)&sHxHi[b * HXS + u4] = hw;
      *(uint2*)&sHxLo[b * HXS + u4] = lw;
      u64 c0q = ALD((u64*)&cb[hbase]);
      u64 c1q = ALD((u64*)&cb[hbase + 2]);
      float4 cf = {__uint_as_float((unsigned)c0q),
                   __uint_as_float((unsigned)(c0q >> 32)),
                   __uint_as_float((unsigned)c1q),
                   __uint_as_float((unsigned)(c1q >> 32))};
      *(float4*)&sCprev[b * CPS + u4] = cf;
    }
    __syncthreads();
  }

  // ---- epilogue: decode final step T-1 (sCprev holds c_{T-1}) ----
  {
    int q = tid >> 5, ks = tid & 31, o = q >> 2, b = q & 3;
    float s = 0.f;
#pragma unroll
    for (int j = 0; j < 16; j++) {
      int k = ks + j * 32;
      s += sLinW[o * CPS + k] * sCprev[b * CPS + k];
    }
    s += __shfl_xor(s, 1);
    s += __shfl_xor(s, 2);
    s += __shfl_xor(s, 4);
    s += __shfl_xor(s, 8);
    s += __shfl_xor(s, 16);
    if (ks == 0)
      out[((size_t)(b0 + b) * T_ + (T_ - 1)) * O_ + wgi * 4 + o] =
          s + sLinB[o];
  }
}

extern "C" void kernel_launch(void* const* d_in, const int* in_sizes, int n_in,
                              void* d_out, int out_size, void* d_ws, size_t ws_size,
                              hipStream_t stream) {
  const float* data = (const float*)d_in[0];
  const float* h0 = (const float*)d_in[1];
  const float* c0 = (const float*)d_in[2];
  const float* W_ih = (const float*)d_in[3];
  const float* W_hh = (const float*)d_in[4];
  const float* b_ih = (const float*)d_in[5];
  const float* b_hh = (const float*)d_in[6];
  const float* lin_W = (const float*)d_in[7];
  const float* lin_b = (const float*)d_in[8];
  float* out = (float*)d_out;
  float* ws = (float*)d_ws;

  // zero the per-group counters (ws is poisoned 0xAA before every call)
  hipMemsetAsync((char*)d_ws + 65536 * 4, 0, NG * 16 * sizeof(int), stream);

  hipLaunchKernelGGL(lstm_fused, dim3(NWG), dim3(NTHR), 0, stream, data, h0, c0,
                     W_ih, W_hh, b_ih, b_hh, lin_W, lin_b, out, ws);
}

// Round 7
// 5505.085 us; speedup vs baseline: 5.3484x; 1.0921x over previous
//
#include <hip/hip_runtime.h>
#include <hip/hip_bf16.h>

// ---------------------------------------------------------------------------
// v4: Fused LSTM (B=32,T=2048,I=128,H=512,O=128), one persistent kernel.
//
// Change vs v3: "data-as-signal" exchange. Per (unit,batch) slot one u64 =
// (c_fp32<<32)|(h_hi16<<16|h_lo16), relaxed agent atomic store. Readers poll
// until low32 != 0xAAAAAAAA (canary). Canary is PROVABLY not a legit hi/lo
// split-bf16 pair (residual exponent must be >=8 below hi's; 0xAAAA|0xAAAA has
// equal exponents). This removes the producer ack-wait, the fetch_add, and
// the flag-poll legs: stores fly while the producer moves on; data arrival IS
// the signal. NBUF=4 rotation; consumed buffers canary-restored by wave7 two
// steps later (safe: WG at step t => all peers consumed buffer (t-2)&3;
// wave7's own vmcnt(0) + 2-step slack orders restore before next fresh).
// One-time init barrier (counter via hipMemsetAsync) makes canary state
// independent of harness poison. 2 raw barriers/step (lgkmcnt-only, no vmcnt
// drain). LDS conflict fixes: HXS 648->656 (MFMA ds_read_b128 4-way -> 2-way
// =free), sGates gate-major (8-way read -> 2-way). c-state + biases in wave0
// registers.
// ---------------------------------------------------------------------------

#define B_ 32
#define T_ 2048
#define I_ 128
#define H_ 512
#define O_ 128
#define NG 8     // batch groups
#define BPG 4    // batches per group
#define WPG 32   // workgroups per group
#define NWG 256
#define NTHR 512
#define NBUF 4

#define HXS 656  // LDS [h|x] row stride (bf16), 640 data + 16 pad (bank-opt)
#define CPS 520  // LDS c_prev / lin_W row stride (floats), 512 + 8 pad
#define CAN 0xAAAAAAAAu

typedef short bf16x8 __attribute__((ext_vector_type(8)));
typedef float f32x4 __attribute__((ext_vector_type(4)));
typedef unsigned long long u64;

static __device__ __forceinline__ unsigned f2bf(float f) {
  unsigned u = __float_as_uint(f);
  u = u + 0x7FFFu + ((u >> 16) & 1u);  // RNE
  return u >> 16;
}
static __device__ __forceinline__ float bf2f(unsigned h) {
  return __uint_as_float(h << 16);
}
static __device__ __forceinline__ float fsigm(float x) {
  return 1.0f / (1.0f + __expf(-x));
}
static __device__ __forceinline__ float ftanh(float x) {
  return 1.0f - 2.0f / (__expf(2.0f * x) + 1.0f);  // safe at +-inf
}

#define ALD(p) __hip_atomic_load((p), __ATOMIC_RELAXED, __HIP_MEMORY_SCOPE_AGENT)
#define AST(p, v) __hip_atomic_store((p), (v), __ATOMIC_RELAXED, __HIP_MEMORY_SCOPE_AGENT)
// Raw workgroup barrier: LDS-drain only, no vmcnt(0) store-ACK serialization.
#define BARRIER() asm volatile("s_waitcnt lgkmcnt(0)\ns_barrier" ::: "memory")

__global__ __launch_bounds__(NTHR, 2) void lstm_fused(
    const float* __restrict__ data, const float* __restrict__ h0,
    const float* __restrict__ c0, const float* __restrict__ W_ih,
    const float* __restrict__ W_hh, const float* __restrict__ b_ih,
    const float* __restrict__ b_hh, const float* __restrict__ lin_W,
    const float* __restrict__ lin_b, float* __restrict__ out,
    float* __restrict__ ws) {
  __shared__ alignas(16) unsigned short sHxHi[BPG * HXS];
  __shared__ alignas(16) unsigned short sHxLo[BPG * HXS];
  __shared__ alignas(16) float sCp[2][BPG * CPS];  // c double-buffer (decode)
  __shared__ alignas(16) float sLinW[4 * CPS];
  __shared__ alignas(16) float sGates[4][2][68];   // [gate][kh][up*4+b]
  __shared__ float sLinB[4];

  const int bid = blockIdx.x;
  const int g = bid & 7;       // batch group
  const int wgi = bid >> 3;    // 0..31 within group
  const int b0 = g * BPG;
  const int ubase = wgi * 16;  // hidden-unit base
  const int tid = threadIdx.x;
  const int lane = tid & 63;
  const int w = tid >> 6;      // wave 0..7
  const int gate = w >> 1;     // i,f,g,o
  const int kh = w & 1;        // K half
  const int m16 = lane & 15;   // MFMA col = batch
  const int kcg = lane >> 4;

  u64* hcPk = (u64*)ws;  // [NBUF][NG][BPG][H] u64 slots (c<<32 | h_pk)
  int* cnt = (int*)(ws + (size_t)NBUF * NG * BPG * H_ * 2);  // init counter

  // ---- one-time preload ----
  bf16x8 fAhi[10], fAlo[10];
  const int grow = gate * H_ + ubase + m16;
#pragma unroll
  for (int kk = 0; kk < 10; kk++) {
    int k = kh * 320 + kk * 32 + kcg * 8;
    const float* src = (k < H_) ? (W_hh + (size_t)grow * H_ + k)
                                : (W_ih + (size_t)grow * I_ + (k - H_));
    float4 v0 = *(const float4*)src;
    float4 v1 = *(const float4*)(src + 4);
    float w8[8] = {v0.x, v0.y, v0.z, v0.w, v1.x, v1.y, v1.z, v1.w};
    union { unsigned short u[8]; bf16x8 v; } hi, lo;
#pragma unroll
    for (int j = 0; j < 8; j++) {
      unsigned h = f2bf(w8[j]);
      hi.u[j] = (unsigned short)h;
      lo.u[j] = (unsigned short)f2bf(w8[j] - bf2f(h));
    }
    fAhi[kk] = hi.v;
    fAlo[kk] = lo.v;
  }
  float bias_[4], c_state = 0.f;
  if (tid < 64) {  // wave0: per-thread (up,b) bias + c-state in registers
    int up = tid >> 2, b = tid & 3;
#pragma unroll
    for (int ga = 0; ga < 4; ga++) {
      int r = ga * H_ + ubase + up;
      bias_[ga] = b_ih[r] + b_hh[r];
    }
    c_state = c0[(size_t)(b0 + b) * H_ + ubase + up];
  }
  for (int idx = tid; idx < 4 * H_; idx += NTHR) {
    int o = idx >> 9, k = idx & (H_ - 1);
    sLinW[o * CPS + k] = lin_W[(size_t)(wgi * 4 + o) * H_ + k];
  }
  if (tid < 4) sLinB[tid] = lin_b[wgi * 4 + tid];

  // stage h0 (split bf16) and x0
  if (tid < 256) {
    int b = tid >> 6, off = (tid & 63) * 8;
    const float* src = h0 + (size_t)(b0 + b) * H_ + off;
    float4 v0 = *(const float4*)src;
    float4 v1 = *(const float4*)(src + 4);
    float w8[8] = {v0.x, v0.y, v0.z, v0.w, v1.x, v1.y, v1.z, v1.w};
    union { unsigned short u[8]; uint4 q; } hi, lo;
#pragma unroll
    for (int j = 0; j < 8; j++) {
      unsigned h = f2bf(w8[j]);
      hi.u[j] = (unsigned short)h;
      lo.u[j] = (unsigned short)f2bf(w8[j] - bf2f(h));
    }
    *(uint4*)&sHxHi[b * HXS + off] = hi.q;
    *(uint4*)&sHxLo[b * HXS + off] = lo.q;
  }
  if (tid >= 256 && tid < 384) {
    int i = tid - 256, b = i >> 5, c4 = i & 31;
    float4 v = *(const float4*)(data + ((size_t)(b0 + b) * T_) * I_ + c4 * 4);
    float w4[4] = {v.x, v.y, v.z, v.w};
    union { unsigned short u[4]; uint2 q; } hi, lo;
#pragma unroll
    for (int j = 0; j < 4; j++) {
      unsigned h = f2bf(w4[j]);
      hi.u[j] = (unsigned short)h;
      lo.u[j] = (unsigned short)f2bf(w4[j] - bf2f(h));
    }
    *(uint2*)&sHxHi[b * HXS + H_ + c4 * 4] = hi.q;
    *(uint2*)&sHxLo[b * HXS + H_ + c4 * 4] = lo.q;
  }
  float4 pfx;
  if (tid >= 320 && tid < 448) {  // pfx = x_1
    int i = tid - 320, b = i >> 5, c4 = i & 31;
    int tp = (T_ > 1) ? 1 : 0;
    pfx = *(const float4*)(data + ((size_t)(b0 + b) * T_ + tp) * I_ + c4 * 4);
  }
  // canary-fill this WG's slots in all NBUF buffers (poison-independent)
  if (tid < 256) {
    int buf = tid >> 6, q = tid & 63, up = q >> 2, b = q & 3;
    AST(&hcPk[(((size_t)buf * NG + g) * BPG + b) * H_ + ubase + up],
        0xAAAAAAAAAAAAAAAAull);
  }
  asm volatile("s_waitcnt vmcnt(0)" ::: "memory");
  __syncthreads();  // full drain: all waves' canary fills ACKed
  if (tid == 0)
    __hip_atomic_fetch_add(&cnt[g * 16], 1, __ATOMIC_RELAXED,
                           __HIP_MEMORY_SCOPE_AGENT);
  if (tid < 64) {  // one-time init barrier: all group WGs canary-ready
    while (ALD(&cnt[g * 16]) < WPG) {}
  }
  __syncthreads();

  const int bcl = (m16 < BPG) ? m16 : (BPG - 1);
  const unsigned short* pBhi = sHxHi + bcl * HXS + kh * 320 + kcg * 8;
  const unsigned short* pBlo = sHxLo + bcl * HXS + kh * 320 + kcg * 8;

  for (int t = 0; t < T_; t++) {
    // ---- MFMA: partial gates for (gate, kh) on staged [h_{t-1}|x_t] ----
    f32x4 a0 = {0.f, 0.f, 0.f, 0.f}, a1 = a0, a2 = a0;
#pragma unroll
    for (int kk = 0; kk < 10; kk++) {
      bf16x8 bh = *(const bf16x8*)(pBhi + kk * 32);
      bf16x8 bl = *(const bf16x8*)(pBlo + kk * 32);
      a0 = __builtin_amdgcn_mfma_f32_16x16x32_bf16(fAhi[kk], bh, a0, 0, 0, 0);
      a1 = __builtin_amdgcn_mfma_f32_16x16x32_bf16(fAhi[kk], bl, a1, 0, 0, 0);
      a2 = __builtin_amdgcn_mfma_f32_16x16x32_bf16(fAlo[kk], bh, a2, 0, 0, 0);
    }
    if (m16 < BPG) {  // C: col=m16(batch), row=kcg*4+j (=up)
#pragma unroll
      for (int j = 0; j < 4; j++) {
        sGates[gate][kh][kcg * 16 + j * 4 + m16] = a0[j] + a1[j] + a2[j];
      }
    }
    BARRIER();  // B1: sGates ready

    // ---- merged post+stage phase (role split) ----
    if (tid < 64) {
      // cell update + fresh u64 store (no ack wait — data IS the signal)
      int up = tid >> 2, b = tid & 3;
      float gi = sGates[0][0][tid] + sGates[0][1][tid] + bias_[0];
      float gf = sGates[1][0][tid] + sGates[1][1][tid] + bias_[1];
      float gg = sGates[2][0][tid] + sGates[2][1][tid] + bias_[2];
      float go = sGates[3][0][tid] + sGates[3][1][tid] + bias_[3];
      float cn = fsigm(gf) * c_state + fsigm(gi) * ftanh(gg);
      float hn = fsigm(go) * ftanh(cn);
      c_state = cn;
      unsigned hh = f2bf(hn);
      unsigned hl = f2bf(hn - bf2f(hh));
      u64 pay = ((u64)__float_as_uint(cn) << 32) | (u64)((hh << 16) | hl);
      AST(&hcPk[(((size_t)(t & 3) * NG + g) * BPG + b) * H_ + ubase + up], pay);
      if (t == T_ - 1) {  // h_f, c_f
        const size_t DEC = (size_t)B_ * T_ * O_;
        out[DEC + (size_t)(b0 + b) * H_ + ubase + up] = hn;
        out[DEC + (size_t)B_ * H_ + (size_t)(b0 + b) * H_ + ubase + up] = cn;
      }
    } else if (tid < 320) {
      // decode step t-1 from sCp[(t-1)&1] (off critical path, LDS only)
      if (t > 0) {
        int q = (tid >> 4) - 4;  // 0..15
        int ks = tid & 15;
        int o = q >> 2, b = q & 3;
        const float* cp = sCp[(t & 1) ^ 1];
        float s = 0.f;
#pragma unroll
        for (int j = 0; j < 32; j++) {
          int k = ks + j * 16;
          s += sLinW[o * CPS + k] * cp[b * CPS + k];
        }
        s += __shfl_xor(s, 1);
        s += __shfl_xor(s, 2);
        s += __shfl_xor(s, 4);
        s += __shfl_xor(s, 8);
        if (ks == 0)
          out[((size_t)(b0 + b) * T_ + (t - 1)) * O_ + wgi * 4 + o] =
              s + sLinB[o];
      }
    } else if (tid < 448) {
      // stage x_{t+1} from pfx; prefetch x_{t+2}
      int i = tid - 320, b = i >> 5, c4 = i & 31;
      union { unsigned short u[4]; uint2 q; } hi, lo;
      float w4[4] = {pfx.x, pfx.y, pfx.z, pfx.w};
#pragma unroll
      for (int j = 0; j < 4; j++) {
        unsigned h = f2bf(w4[j]);
        hi.u[j] = (unsigned short)h;
        lo.u[j] = (unsigned short)f2bf(w4[j] - bf2f(h));
      }
      *(uint2*)&sHxHi[b * HXS + H_ + c4 * 4] = hi.q;
      *(uint2*)&sHxLo[b * HXS + H_ + c4 * 4] = lo.q;
      int tp = (t + 2 < T_) ? t + 2 : T_ - 1;
      pfx = *(const float4*)(data + ((size_t)(b0 + b) * T_ + tp) * I_ + c4 * 4);
    } else {
      // wave7: canary-restore buffer (t-2)&3 (all peers consumed it)
      if (t >= 2) {
        int q = tid - 448, up7 = q >> 2, b7 = q & 3;
        AST(&hcPk[(((size_t)((t - 2) & 3) * NG + g) * BPG + b7) * H_ + ubase +
                  up7],
            0xAAAAAAAAAAAAAAAAull);
        asm volatile("s_waitcnt vmcnt(0)" ::: "memory");  // bound restore
      }
    }

    // ---- staging: poll-read h_t|c_t (data-as-signal), unpack to LDS ----
    {
      int b = tid >> 7, u4 = (tid & 127) * 4;
      const u64* sp =
          hcPk + (((size_t)(t & 3) * NG + g) * BPG + b) * H_ + u4;
      u64 v0, v1, v2, v3;
      for (;;) {
        v0 = ALD(sp);
        v1 = ALD(sp + 1);
        v2 = ALD(sp + 2);
        v3 = ALD(sp + 3);
        if (((unsigned)v0 != CAN) & ((unsigned)v1 != CAN) &
            ((unsigned)v2 != CAN) & ((unsigned)v3 != CAN))
          break;
      }
      unsigned p0 = (unsigned)v0, p1 = (unsigned)v1, p2 = (unsigned)v2,
               p3 = (unsigned)v3;
      uint2 hw = {(p0 >> 16) | (p1 & 0xFFFF0000u),
                  (p2 >> 16) | (p3 & 0xFFFF0000u)};
      uint2 lw = {(p0 & 0xFFFFu) | (p1 << 16),
                  (p2 & 0xFFFFu) | (p3 << 16)};
      *(uint2*)&sHxHi[b * HXS + u4] = hw;
      *(uint2*)&sHxLo[b * HXS + u4] = lw;
      float4 cf = {__uint_as_float((unsigned)(v0 >> 32)),
                   __uint_as_float((unsigned)(v1 >> 32)),
                   __uint_as_float((unsigned)(v2 >> 32)),
                   __uint_as_float((unsigned)(v3 >> 32))};
      *(float4*)&sCp[t & 1][b * CPS + u4] = cf;
    }
    BARRIER();  // B2: sHxHi/Lo + sCp ready for next step
  }

  // ---- epilogue: decode final step T-1 (sCp[(T-1)&1] holds c_{T-1}) ----
  {
    int q = tid >> 5, ks = tid & 31, o = q >> 2, b = q & 3;
    const float* cp = sCp[(T_ - 1) & 1];
    float s = 0.f;
#pragma unroll
    for (int j = 0; j < 16; j++) {
      int k = ks + j * 32;
      s += sLinW[o * CPS + k] * cp[b * CPS + k];
    }
    s += __shfl_xor(s, 1);
    s += __shfl_xor(s, 2);
    s += __shfl_xor(s, 4);
    s += __shfl_xor(s, 8);
    s += __shfl_xor(s, 16);
    if (ks == 0)
      out[((size_t)(b0 + b) * T_ + (T_ - 1)) * O_ + wgi * 4 + o] =
          s + sLinB[o];
  }
}

extern "C" void kernel_launch(void* const* d_in, const int* in_sizes, int n_in,
                              void* d_out, int out_size, void* d_ws, size_t ws_size,
                              hipStream_t stream) {
  const float* data = (const float*)d_in[0];
  const float* h0 = (const float*)d_in[1];
  const float* c0 = (const float*)d_in[2];
  const float* W_ih = (const float*)d_in[3];
  const float* W_hh = (const float*)d_in[4];
  const float* b_ih = (const float*)d_in[5];
  const float* b_hh = (const float*)d_in[6];
  const float* lin_W = (const float*)d_in[7];
  const float* lin_b = (const float*)d_in[8];
  float* out = (float*)d_out;
  float* ws = (float*)d_ws;

  // zero the one-time init counters (slots region after 512KB of buffers)
  const size_t CNT_OFF = (size_t)NBUF * NG * BPG * H_ * 8;  // 524288
  hipMemsetAsync((char*)d_ws + CNT_OFF, 0, NG * 16 * sizeof(int), stream);

  hipLaunchKernelGGL(lstm_fused, dim3(NWG), dim3(NTHR), 0, stream, data, h0, c0,
                     W_ih, W_hh, b_ih, b_hh, lin_W, lin_b, out, ws);
}